// Round 1
// baseline (1372.407 us; speedup 1.0000x reference)
//
#include <hip/hip_runtime.h>
#include <math.h>

// Problem constants
#define NTOT 32768   // T*B
#define CIN  201
#define S    67      // keypoints (seq len)
#define E    8
#define H    2
#define L    12
#define FF   16
#define OUTC 128
#define KF   536     // S*E
#define EPB  7       // elements per block
#define LPE  34      // lanes per element; lane j owns rows 2j, 2j+1 (row 67 = pad)
#define THREADS 256  // 7*34 = 238 active (93%)
#define NPAIR 34     // t-pair slots; slot 33 = {t=66 real, t=67 zero-pad}

typedef float v2f __attribute__((ext_vector_type(2)));
typedef __fp16 h2  __attribute__((ext_vector_type(2)));

#if __has_builtin(__builtin_amdgcn_exp2f)
#define EXP2F(x) __builtin_amdgcn_exp2f(x)
#else
#define EXP2F(x) exp2f(x)
#endif
#if __has_builtin(__builtin_amdgcn_rcpf)
#define RCPF(x) __builtin_amdgcn_rcpf(x)
#else
#define RCPF(x) (1.0f/(x))
#endif
#if __has_builtin(__builtin_amdgcn_rsqf)
#define RSQF(x) __builtin_amdgcn_rsqf(x)
#else
#define RSQF(x) rsqrtf(x)
#endif

// f32 pair -> packed f16 pair (one v_cvt_pkrtz_f16_f32)
#if __has_builtin(__builtin_amdgcn_cvt_pkrtz)
__device__ __forceinline__ h2 cvh(float a, float b) {
    return __builtin_amdgcn_cvt_pkrtz(a, b);
}
#else
__device__ __forceinline__ h2 cvh(float a, float b) {
    h2 r; r.x = (__fp16)a; r.y = (__fp16)b; return r;
}
#endif
__device__ __forceinline__ float pkf(float a, float b) {
    return __builtin_bit_cast(float, cvh(a, b));
}
__device__ __forceinline__ h2 bch(float f) { return __builtin_bit_cast(h2, f); }

// fp32 += dot2(f16 pair, f16 pair): v_dot2_f32_f16, 2 MACs / instruction
#if __has_builtin(__builtin_amdgcn_fdot2)
#define FDOT2(a, b, c) __builtin_amdgcn_fdot2((a), (b), (c), false)
#else
#define FDOT2(a, b, c) ((float)(a).x*(float)(b).x + (float)(a).y*(float)(b).y + (c))
#endif

// 0.5 (=1/sqrt(DH)) * log2(e)
#define QSCALE 0.7213475204444817f

__device__ __forceinline__ v2f sp(float x) { return (v2f){x, x}; }

__device__ __forceinline__ void ln8p(v2f* x, const float* __restrict__ gg,
                                     const float* __restrict__ bb) {
    v2f m = {0.f, 0.f};
    #pragma unroll
    for (int e = 0; e < E; ++e) m += x[e];
    m *= 0.125f;
    v2f v = {0.f, 0.f};
    #pragma unroll
    for (int e = 0; e < E; ++e) { v2f d = x[e] - m; v += d * d; }
    v *= 0.125f;
    v2f rs;
    rs.x = RSQF(v.x + 1e-5f);
    rs.y = RSQF(v.y + 1e-5f);
    #pragma unroll
    for (int e = 0; e < E; ++e) x[e] = (x[e] - m) * rs * sp(gg[e]) + sp(bb[e]);
}

__global__ __launch_bounds__(THREADS, 8)
void enc_kernel(const float* __restrict__ pose,
                const float* __restrict__ ew,  const float* __restrict__ ebias,
                const float* __restrict__ ipw, const float* __restrict__ ipb,
                const float* __restrict__ aow, const float* __restrict__ aob,
                const float* __restrict__ f1w, const float* __restrict__ f1b,
                const float* __restrict__ f2w, const float* __restrict__ f2b,
                const float* __restrict__ g1,  const float* __restrict__ b1,
                const float* __restrict__ g2,  const float* __restrict__ b2,
                float* __restrict__ xf)
{
    // f16-packed t-pair interleaved K/V; slot i holds t-pair {2i, 2i+1}.
    // Kh[gh][i] = {k01_t0, k23_t0, k01_t1, k23_t1}  (each float = packed h2)
    // Vh[gh][i] = {v0_{t0,t1}, v1_{t0,t1}, v2_{t0,t1}, v3_{t0,t1}}
    // 2 * 14 * 34 * 16 B = 15232 B -> 8 blocks/CU (thread-capped, 100% occ).
    __shared__ float4 Kh[EPB * H][NPAIR];
    __shared__ float4 Vh[EPB * H][NPAIR];

    const int lid = threadIdx.x;
    const int g   = lid / LPE;          // element in block (0..6 valid)
    const int j   = lid - g * LPE;      // pair index (0..33)
    const int n   = blockIdx.x * EPB + g;
    const bool active = (g < EPB) && (n < NTOT);
    const bool pad = (j == LPE - 1);    // lane 33: r1 = row 67 (doesn't exist)
    const int r0 = 2 * j;

    // ---- embed (rows r0=2j, r1=2j+1 packed into halves) ----
    v2f xr[E];
    if (active) {
        const float* p0 = pose + (size_t)n * CIN + 3 * r0;
        const float* p1 = pad ? p0 : (p0 + 3);
        v2f c0 = {p0[0], p1[0]};
        v2f c1 = {p0[1], p1[1]};
        v2f c2 = {p0[2], p1[2]};
        #pragma unroll
        for (int e = 0; e < E; ++e)
            xr[e] = sp(ebias[e]) + c0 * sp(ew[e*3+0]) + c1 * sp(ew[e*3+1])
                                 + c2 * sp(ew[e*3+2]);
    }

    #pragma unroll 1
    for (int l = 0; l < L; ++l) {
        const float* W  = ipw + l * 192;   // [24][8] row-major, wave-uniform
        const float* Bq = ipb + l * 24;

        h2 qh[8];   // per head h: {q01_r0, q23_r0, q01_r1, q23_r1}
        if (active) {
            // ---- K,V (rows 8..23) first: short live range, straight to LDS ----
            v2f kv[16];
            #pragma unroll
            for (int jo = 0; jo < 16; ++jo) {
                v2f a = sp(Bq[8 + jo]);
                #pragma unroll
                for (int e = 0; e < E; ++e) a += xr[e] * sp(W[(8+jo)*8 + e]);
                kv[jo] = a;
            }
            if (pad) {   // row 67: k=0 (exp2(0)=1, fixed by lsum-1), v=0
                #pragma unroll
                for (int c = 0; c < 16; ++c) kv[c].y = 0.f;
            }
            #pragma unroll
            for (int h = 0; h < H; ++h) {
                const int gh = g*2 + h;
                Kh[gh][j] = make_float4(
                    pkf(kv[4*h+0].x, kv[4*h+1].x),
                    pkf(kv[4*h+2].x, kv[4*h+3].x),
                    pkf(kv[4*h+0].y, kv[4*h+1].y),
                    pkf(kv[4*h+2].y, kv[4*h+3].y));
                Vh[gh][j] = make_float4(
                    pkf(kv[8+4*h+0].x, kv[8+4*h+0].y),
                    pkf(kv[8+4*h+1].x, kv[8+4*h+1].y),
                    pkf(kv[8+4*h+2].x, kv[8+4*h+2].y),
                    pkf(kv[8+4*h+3].x, kv[8+4*h+3].y));
            }
            // ---- Q (rows 0..7), scaled and packed to f16 pairs ----
            #pragma unroll
            for (int h = 0; h < H; ++h) {
                v2f q[4];
                #pragma unroll
                for (int c = 0; c < 4; ++c) {
                    v2f a = sp(Bq[4*h + c]);
                    #pragma unroll
                    for (int e = 0; e < E; ++e) a += xr[e] * sp(W[(4*h+c)*8 + e]);
                    q[c] = a * QSCALE;
                }
                qh[4*h+0] = cvh(q[0].x, q[1].x);   // dims 0-1, row r0
                qh[4*h+1] = cvh(q[2].x, q[3].x);   // dims 2-3, row r0
                qh[4*h+2] = cvh(q[0].y, q[1].y);   // dims 0-1, row r1
                qh[4*h+3] = cvh(q[2].y, q[3].y);   // dims 2-3, row r1
            }
        }
        __syncthreads();

        if (active) {
            const h2 one2 = cvh(1.0f, 1.0f);
            v2f os[E];   // os[e] = {o[r0][e], o[r1][e]}
            #pragma unroll
            for (int h = 0; h < H; ++h) {
                const int gh = g*2 + h;
                const float4* pK = Kh[gh];
                const float4* pV = Vh[gh];
                const h2 q01_0 = qh[4*h+0], q23_0 = qh[4*h+1];
                const h2 q01_1 = qh[4*h+2], q23_1 = qh[4*h+3];
                float ls0 = 0.f, ls1 = 0.f;
                float oc00=0.f, oc01=0.f, oc02=0.f, oc03=0.f;
                float oc10=0.f, oc11=0.f, oc12=0.f, oc13=0.f;
                #pragma unroll
                for (int i = 0; i < NPAIR; ++i) {     // t = 0..67 (67 = zero-pad)
                    float4 kk = pK[i];
                    float4 vv = pV[i];
                    h2 ka = bch(kk.x), kb = bch(kk.y);   // t0: dims 01, 23
                    h2 kc = bch(kk.z), kd = bch(kk.w);   // t1: dims 01, 23
                    float s00 = FDOT2(q01_0, ka, FDOT2(q23_0, kb, 0.f));
                    float s01 = FDOT2(q01_0, kc, FDOT2(q23_0, kd, 0.f));
                    float s10 = FDOT2(q01_1, ka, FDOT2(q23_1, kb, 0.f));
                    float s11 = FDOT2(q01_1, kc, FDOT2(q23_1, kd, 0.f));
                    float e00 = EXP2F(s00), e01 = EXP2F(s01);
                    float e10 = EXP2F(s10), e11 = EXP2F(s11);
                    h2 ep0 = cvh(e00, e01);    // row r0, {t0,t1}
                    h2 ep1 = cvh(e10, e11);    // row r1
                    ls0 = FDOT2(ep0, one2, ls0);
                    ls1 = FDOT2(ep1, one2, ls1);
                    h2 v0 = bch(vv.x), v1 = bch(vv.y);
                    h2 v2 = bch(vv.z), v3 = bch(vv.w);
                    oc00 = FDOT2(ep0, v0, oc00); oc01 = FDOT2(ep0, v1, oc01);
                    oc02 = FDOT2(ep0, v2, oc02); oc03 = FDOT2(ep0, v3, oc03);
                    oc10 = FDOT2(ep1, v0, oc10); oc11 = FDOT2(ep1, v1, oc11);
                    oc12 = FDOT2(ep1, v2, oc12); oc13 = FDOT2(ep1, v3, oc13);
                }
                float l0 = ls0 - 1.0f;   // remove pad's exp2(0)=1
                float l1 = ls1 - 1.0f;
                float i0 = RCPF(l0), i1 = RCPF(l1);
                os[4*h+0] = (v2f){oc00*i0, oc10*i1};
                os[4*h+1] = (v2f){oc01*i0, oc11*i1};
                os[4*h+2] = (v2f){oc02*i0, oc12*i1};
                os[4*h+3] = (v2f){oc03*i0, oc13*i1};
            }

            // attn_out + residual + LN1
            {
                const float* WA = aow + l*64;   // [8][8]
                const float* BA = aob + l*8;
                #pragma unroll
                for (int e = 0; e < E; ++e) {
                    v2f a = sp(BA[e]);
                    #pragma unroll
                    for (int e2 = 0; e2 < E; ++e2) a += os[e2] * sp(WA[e*8 + e2]);
                    xr[e] += a;
                }
            }
            ln8p(xr, g1 + l*E, b1 + l*E);

            // FF
            {
                const float* W1 = f1w + l*128;  // [16][8]
                const float* B1 = f1b + l*16;
                const float* W2 = f2w + l*128;  // [8][16]
                const float* B2 = f2b + l*8;
                v2f t1[FF];
                #pragma unroll
                for (int f = 0; f < FF; ++f) {
                    v2f a = sp(B1[f]);
                    #pragma unroll
                    for (int e = 0; e < E; ++e) a += xr[e] * sp(W1[f*8 + e]);
                    a.x = fmaxf(a.x, 0.f);
                    a.y = fmaxf(a.y, 0.f);
                    t1[f] = a;
                }
                #pragma unroll
                for (int e = 0; e < E; ++e) {
                    v2f a = sp(B2[e]);
                    #pragma unroll
                    for (int f = 0; f < FF; ++f) a += t1[f] * sp(W2[e*16 + f]);
                    xr[e] += a;
                }
            }
            ln8p(xr, g2 + l*E, b2 + l*E);
        }
        __syncthreads();   // protect K/V before next layer overwrites
    }

    if (active) {
        float* dst = xf + (size_t)n * KF + r0 * E;   // rows 2j,2j+1 contiguous
        *(float4*)(dst + 0) = make_float4(xr[0].x, xr[1].x, xr[2].x, xr[3].x);
        *(float4*)(dst + 4) = make_float4(xr[4].x, xr[5].x, xr[6].x, xr[7].x);
        if (!pad) {
            *(float4*)(dst + 8)  = make_float4(xr[0].y, xr[1].y, xr[2].y, xr[3].y);
            *(float4*)(dst + 12) = make_float4(xr[4].y, xr[5].y, xr[6].y, xr[7].y);
        }
    }
}

// wt[k][c] = ow[c][k]
__global__ void tr_kernel(const float* __restrict__ ow, float* __restrict__ wt)
{
    int i = blockIdx.x * 256 + threadIdx.x;
    if (i < OUTC * KF) {
        int c = i / KF, k = i - c * KF;
        wt[k * OUTC + c] = ow[i];
    }
}

// out = tanh(Xf[32768,536] @ Wt[536,128] + b)
__global__ __launch_bounds__(256, 4)
void out_kernel(const float* __restrict__ xf, const float* __restrict__ wt,
                const float* __restrict__ ob, float* __restrict__ out)
{
    __shared__ float Xs[32][68];
    const int lid = threadIdx.x;
    const int tx  = lid & 31;
    const int ty  = lid >> 5;
    const int n0  = blockIdx.x * 32;

    float acc[4][4] = {};

    #pragma unroll 1
    for (int kc = 0; kc < 9; ++kc) {
        const int kb = kc * 64;
        const int kw = (kc < 8) ? 64 : 24;
        __syncthreads();
        const int nvec = 32 * (kw >> 2);
        for (int i = lid; i < nvec; i += 256) {
            int r = i / (kw >> 2), kq = i - r * (kw >> 2);
            *(float4*)&Xs[r][kq*4] =
                *(const float4*)&xf[(size_t)(n0 + r) * KF + kb + kq*4];
        }
        __syncthreads();
        #pragma unroll 4
        for (int k = 0; k < kw; ++k) {
            float4 w4 = *(const float4*)&wt[(size_t)(kb + k) * OUTC + tx*4];
            #pragma unroll
            for (int i = 0; i < 4; ++i) {
                float x = Xs[ty*4 + i][k];
                acc[i][0] += x*w4.x; acc[i][1] += x*w4.y;
                acc[i][2] += x*w4.z; acc[i][3] += x*w4.w;
            }
        }
    }

    const float4 bb = *(const float4*)&ob[tx*4];
    #pragma unroll
    for (int i = 0; i < 4; ++i) {
        int r = n0 + ty*4 + i;
        float4 v;
        v.x = tanhf(acc[i][0] + bb.x);
        v.y = tanhf(acc[i][1] + bb.y);
        v.z = tanhf(acc[i][2] + bb.z);
        v.w = tanhf(acc[i][3] + bb.w);
        *(float4*)(out + (size_t)r * OUTC + tx*4) = v;
    }
}

extern "C" void kernel_launch(void* const* d_in, const int* in_sizes, int n_in,
                              void* d_out, int out_size, void* d_ws, size_t ws_size,
                              hipStream_t stream) {
    (void)in_sizes; (void)n_in; (void)out_size; (void)ws_size;
    const float* pose = (const float*)d_in[0];
    const float* ew   = (const float*)d_in[1];
    const float* eb   = (const float*)d_in[2];
    const float* ipw  = (const float*)d_in[3];
    const float* ipb  = (const float*)d_in[4];
    const float* aow  = (const float*)d_in[5];
    const float* aob  = (const float*)d_in[6];
    const float* f1w  = (const float*)d_in[7];
    const float* f1b  = (const float*)d_in[8];
    const float* f2w  = (const float*)d_in[9];
    const float* f2b  = (const float*)d_in[10];
    const float* g1   = (const float*)d_in[11];
    const float* b1   = (const float*)d_in[12];
    const float* g2   = (const float*)d_in[13];
    const float* b2   = (const float*)d_in[14];
    const float* ow   = (const float*)d_in[15];
    const float* ob   = (const float*)d_in[16];

    float* xf = (float*)d_ws;                               // 70.25 MB
    float* wt = xf + (size_t)NTOT * KF;                     // 268 KB

    const int grid1 = (NTOT + EPB - 1) / EPB;               // 4682
    enc_kernel<<<grid1, THREADS, 0, stream>>>(pose, ew, eb, ipw, ipb, aow, aob,
                                              f1w, f1b, f2w, f2b, g1, b1, g2, b2, xf);
    tr_kernel<<<(OUTC*KF + 255)/256, 256, 0, stream>>>(ow, wt);
    out_kernel<<<NTOT / 32, 256, 0, stream>>>(xf, wt, ob, (float*)d_out);
}